// Round 1
// baseline (1451.988 us; speedup 1.0000x reference)
//
#include <hip/hip_runtime.h>
#include <math.h>

// Problem constants (fixed by the reference)
#define NN 1024   // nodes
#define BB 32     // mols
#define EE 8192   // edges
#define DD 64     // DIM
#define ID 66     // IN_DIM
#define FT 63     // feats dim
#define CAP 128   // max nnz per adj column (data: <=32, same-batch only)
#define MAXM 64   // max nodes per mol    (data: exactly 32)

// ---- workspace layout (float offsets) ----
enum : int {
  OFF_ACC   = 0,                       // N*4   coor segsum accumulator
  OFF_MI    = OFF_ACC + NN*4,          // N*64  m_i accumulator (63 used)
  OFF_DEG   = OFF_MI + NN*64,          // N     degree (float)
  OFF_SMIP  = OFF_DEG + NN,            // N*66  pre-BN smi
  OFF_OUT   = OFF_SMIP + NN*ID,        // N*66  h == out (always equal in ref)
  OFF_STATS = OFF_OUT + NN*ID,         // 144   mean[66], rstd[66]
  OFF_Q     = OFF_STATS + 144,         // 726*66 augmented NNConv weight
  OFF_MAGG  = OFF_Q + 47920,           // N*66  per-iter message aggregate
  OFF_M     = OFF_MAGG + NN*ID,        // N*66  m buffer
  OFF_CM    = OFF_M + NN*ID,           // N*132 cm = [m(66), sp(64)] stride 132
  OFF_QSTAR = OFF_CM + NN*132,         // 32*132
  OFF_CVAL  = OFF_QSTAR + BB*132,      // N*CAP csc values
  OFF_FEND  = OFF_CVAL + NN*CAP
};
enum : int {  // int region, starts at ws + OFF_FEND
  IOFF_CNT  = 0,        // N
  IOFF_CIDX = NN,       // N*CAP
  IOFF_END  = NN + NN*CAP
};

__device__ __forceinline__ float sgm(float x){ return 1.0f/(1.0f+expf(-x)); }
__device__ __forceinline__ float silu_(float x){ return x/(1.0f+expf(-x)); }
__device__ __forceinline__ float nan0(float v){ return (v!=v) ? 0.0f : v; }

// ---- zero accumulators (ws is re-poisoned 0xAA before every launch) ----
__global__ void k_zero(float* __restrict__ ws, int* __restrict__ iw){
  int i = blockIdx.x*256 + threadIdx.x;
  if (i < OFF_SMIP) ws[i] = 0.f;          // ACC, MI, DEG are contiguous
  if (i < NN) iw[IOFF_CNT + i] = 0;
}

// ---- A1: per-edge EGNN MLP chain + atomic scatter ----
#define EB 16
__global__ __launch_bounds__(256) void k_edge(
    const float* __restrict__ mnc, const int* __restrict__ eidx,
    const float* __restrict__ e1w, const float* __restrict__ e1b,
    const float* __restrict__ e2w, const float* __restrict__ e2b,
    const float* __restrict__ c1w, const float* __restrict__ c1b,
    const float* __restrict__ c2w, const float* __restrict__ c2b,
    float* __restrict__ ws)
{
  __shared__ float xin[EB][132];   // 127 used (padded stride vs bank conflicts)
  __shared__ float eh [EB][260];   // 254 used
  __shared__ float mij[EB][68];    // 63 used
  __shared__ float ch [EB][260];   // 252 used
  __shared__ int   ssrc[EB], sdst[EB];
  __shared__ float srel[EB][4];
  int tid = threadIdx.x;
  int e0 = blockIdx.x*EB;
  if (tid < EB){
    int e = e0 + tid;
    int s = eidx[e], d = eidx[EE + e];
    ssrc[tid]=s; sdst[tid]=d;
    float rd = 0.f;
    #pragma unroll
    for (int k=0;k<3;k++){ float r = mnc[s*ID+k]-mnc[d*ID+k]; srel[tid][k]=r; rd += r*r; }
    xin[tid][126] = rd;
  }
  __syncthreads();
  for (int idx=tid; idx<EB*126; idx+=256){
    int e = idx/126, j = idx%126;
    int node = (j < FT) ? sdst[e] : ssrc[e];
    int jj   = (j < FT) ? j : (j-FT);
    xin[e][j] = mnc[node*ID + 3 + jj];
  }
  __syncthreads();
  for (int idx=tid; idx<EB*254; idx+=256){     // eh = silu(e1)
    int e = idx & 15, u = idx >> 4;
    float s = e1b[u];
    const float* w = e1w + u*127;
    for (int j=0;j<127;j++) s += xin[e][j]*w[j];
    eh[e][u] = silu_(s);
  }
  __syncthreads();
  for (int idx=tid; idx<EB*FT; idx+=256){      // m_ij = silu(e2), scatter to MI
    int e = idx & 15, u = idx >> 4;
    float s = e2b[u];
    const float* w = e2w + u*254;
    for (int j=0;j<254;j++) s += eh[e][j]*w[j];
    float v = silu_(s);
    mij[e][u] = v;
    atomicAdd(ws + OFF_MI + sdst[e]*64 + u, v);
  }
  if (tid < EB) atomicAdd(ws + OFF_DEG + sdst[tid], 1.0f);
  __syncthreads();
  for (int idx=tid; idx<EB*252; idx+=256){     // ch = silu(c1)
    int e = idx & 15, u = idx >> 4;
    float s = c1b[u];
    const float* w = c1w + u*FT;
    for (int j=0;j<FT;j++) s += mij[e][j]*w[j];
    ch[e][u] = silu_(s);
  }
  __syncthreads();
  if (tid < EB*4){                             // cw scalar, coor scatter
    int e = tid >> 2, q = tid & 3;
    float s = 0.f;
    for (int j=q; j<252; j+=4) s += ch[e][j]*c2w[j];
    s += __shfl_down(s, 1, 64);
    s += __shfl_down(s, 2, 64);
    if (q == 0){
      float cw = s + c2b[0];
      #pragma unroll
      for (int k=0;k<3;k++) atomicAdd(ws + OFF_ACC + sdst[e]*4 + k, cw*srel[e][k]);
    }
  }
}

// ---- A2: node MLP -> smi_pre (with coors_out and nan->0) ----
#define NB 16
__global__ __launch_bounds__(256) void k_node(
    const float* __restrict__ mnc,
    const float* __restrict__ n1w, const float* __restrict__ n1b,
    const float* __restrict__ n2w, const float* __restrict__ n2b,
    float* __restrict__ ws)
{
  __shared__ float xin[NB][132];  // 126 used: [feats(63), m_i(63)]
  __shared__ float t1 [NB][132];  // 126 used
  int tid = threadIdx.x;
  int n0 = blockIdx.x*NB;
  for (int idx=tid; idx<NB*126; idx+=256){
    int e = idx/126, j = idx%126;
    int node = n0 + e;
    xin[e][j] = (j < FT) ? mnc[node*ID + 3 + j] : ws[OFF_MI + node*64 + (j-FT)];
  }
  __syncthreads();
  for (int idx=tid; idx<NB*126; idx+=256){
    int e = idx & 15, u = idx >> 4;
    float s = n1b[u];
    const float* w = n1w + u*126;
    for (int j=0;j<126;j++) s += xin[e][j]*w[j];
    t1[e][u] = silu_(s);
  }
  __syncthreads();
  for (int idx=tid; idx<NB*FT; idx+=256){
    int e = idx & 15, u = idx >> 4;
    float s = n2b[u];
    const float* w = n2w + u*126;
    for (int j=0;j<126;j++) s += t1[e][j]*w[j];
    int node = n0 + e;
    ws[OFF_SMIP + node*ID + 3 + u] = nan0(xin[e][u] + s);   // feats + lin
  }
  if (tid < NB*3){
    int e = tid/3, k = tid%3;
    int node = n0 + e;
    ws[OFF_SMIP + node*ID + k] = nan0(mnc[node*ID + k] + ws[OFF_ACC + node*4 + k]);
  }
}

// ---- A3: batchnorm over all N rows, per column ----
__global__ __launch_bounds__(256) void k_bn_stats(float* __restrict__ ws){
  __shared__ float scr[8];
  int j = blockIdx.x, tid = threadIdx.x;
  float s=0.f, ss=0.f;
  for (int i=tid; i<NN; i+=256){ float x = ws[OFF_SMIP + i*ID + j]; s+=x; ss+=x*x; }
  for (int o=32;o>0;o>>=1){ s += __shfl_down(s,o,64); ss += __shfl_down(ss,o,64); }
  int w = tid>>6;
  if ((tid&63)==0){ scr[w]=s; scr[4+w]=ss; }
  __syncthreads();
  if (tid==0){
    float S=0,SS=0;
    for (int q=0;q<4;q++){S+=scr[q];SS+=scr[4+q];}
    float mean = S/NN;
    float var  = SS/NN - mean*mean;
    ws[OFF_STATS + j]      = mean;
    ws[OFF_STATS + 66 + j] = 1.0f/sqrtf(var + 1e-5f);
  }
}
__global__ void k_bn_apply(const float* __restrict__ bng, const float* __restrict__ bnb,
                           float* __restrict__ ws){
  int idx = blockIdx.x*256 + threadIdx.x;
  if (idx < NN*ID){
    int j = idx % ID;
    ws[OFF_OUT + idx] = bng[j]*(ws[OFF_SMIP+idx]-ws[OFF_STATS+j])*ws[OFF_STATS+66+j] + bnb[j];
  }
}

// ---- build augmented NNConv weight Q[(i*11+t), o] (t==10 slot carries nn_b) ----
__global__ void k_buildq(const float* __restrict__ nnw, const float* __restrict__ nnb,
                         float* __restrict__ ws){
  int idx = blockIdx.x*256 + threadIdx.x;
  if (idx < 726*ID){
    int k = idx/ID, o = idx%ID;
    int i = k/11, t = k%11;
    ws[OFF_Q + idx] = (t<10) ? nnw[(i*ID+o)*10 + t] : nnb[i*ID+o];
  }
}

// ---- CSC of adj (data-adaptive sparsity; correct for any adj with <=CAP nnz/col) ----
__global__ void k_csc(const float* __restrict__ adj, float* __restrict__ ws, int* __restrict__ iw){
  int idx = blockIdx.x*256 + threadIdx.x;
  if (idx < NN*NN){
    float v = adj[idx];
    if (v != 0.0f){
      int a = idx % NN, b = idx / NN;
      int p = atomicAdd(iw + IOFF_CNT + a, 1);
      if (p < CAP){ iw[IOFF_CIDX + a*CAP + p] = b; ws[OFF_CVAL + a*CAP + p] = v; }
    }
  }
}

__global__ void k_zero_magg(float* __restrict__ ws){
  int i = blockIdx.x*256 + threadIdx.x;
  if (i < NN*ID) ws[OFF_MAGG + i] = 0.f;
}

// ---- B1+B2: msg[e,o] = sum_k P[e,k] Q[k,o], P built on the fly; scatter into MAGG ----
#define MEB 64
__global__ __launch_bounds__(256) void k_msg(
    const float* __restrict__ ea, const int* __restrict__ eidx, float* __restrict__ ws)
{
  __shared__ float xs [MEB][68];   // out[src[e]]
  __shared__ float eas[MEB][12];   // edge_attr ++ [1]
  __shared__ float qc [66][68];    // Q chunk (66 k's x 66 o's)
  __shared__ int ssrc[MEB], sdst[MEB];
  int tid = threadIdx.x;
  int e0 = blockIdx.x*MEB;
  if (tid < MEB){ ssrc[tid]=eidx[e0+tid]; sdst[tid]=eidx[EE+e0+tid]; }
  __syncthreads();
  for (int idx=tid; idx<MEB*ID; idx+=256){ int e=idx/ID, i=idx%ID; xs[e][i]=ws[OFF_OUT+ssrc[e]*ID+i]; }
  for (int idx=tid; idx<MEB*11; idx+=256){ int e=idx/11, t=idx%11; eas[e][t] = (t<10)? ea[(e0+e)*10+t] : 1.0f; }
  float acc[17];
  #pragma unroll
  for (int s=0;s<17;s++) acc[s]=0.f;
  for (int c=0;c<11;c++){
    __syncthreads();
    for (int idx=tid; idx<66*ID; idx+=256){ int kk=idx/ID, o=idx%ID; qc[kk][o]=ws[OFF_Q+(c*66+kk)*ID+o]; }
    __syncthreads();
    #pragma unroll
    for (int s=0;s<17;s++){
      int oi = tid + s*256;
      if (oi < MEB*ID){
        int e = oi/ID, o = oi%ID;
        float a = acc[s];
        #pragma unroll
        for (int ii=0; ii<6; ii++){
          float xv = xs[e][c*6+ii];
          #pragma unroll
          for (int t=0;t<11;t++) a += xv*eas[e][t]*qc[ii*11+t][o];
        }
        acc[s] = a;
      }
    }
  }
  __syncthreads();
  #pragma unroll
  for (int s=0;s<17;s++){
    int oi = tid + s*256;
    if (oi < MEB*ID){
      int e = oi/ID, o = oi%ID;
      atomicAdd(ws + OFF_MAGG + sdst[e]*ID + o, acc[s]);
    }
  }
}

// ---- B3: m = relu(magg/deg + out@root + nn_bias) ----
__global__ __launch_bounds__(256) void k_mnode(
    const float* __restrict__ root, const float* __restrict__ nnbias, float* __restrict__ ws)
{
  __shared__ float rs[66][68];
  __shared__ float xo[NB][68];
  int tid = threadIdx.x;
  int n0 = blockIdx.x*NB;
  for (int idx=tid; idx<66*ID; idx+=256){ int j=idx/ID, o=idx%ID; rs[j][o]=root[idx]; }
  for (int idx=tid; idx<NB*ID; idx+=256){ int e=idx/ID, j=idx%ID; xo[e][j]=ws[OFF_OUT+(n0+e)*ID+j]; }
  __syncthreads();
  for (int idx=tid; idx<NB*ID; idx+=256){
    int e = idx & 15, o = idx >> 4;
    int node = n0 + e;
    float s = nnbias[o] + ws[OFF_MAGG + node*ID + o] / fmaxf(ws[OFF_DEG + node], 1.0f);
    for (int j=0;j<ID;j++) s += xo[e][j]*rs[j][o];
    s = fmaxf(s, 0.0f);
    ws[OFF_M  + node*ID + o] = s;
    ws[OFF_CM + node*132 + o] = s;
  }
}

// ---- B4: fused t0 -> mid (sparse adj column) -> conv2 -> sp, one block per node a ----
__global__ __launch_bounds__(256) void k_spconv(
    const float* __restrict__ c1w, const float* __restrict__ c1b,
    const float* __restrict__ c2w, const float* __restrict__ c2b,
    int it, float* __restrict__ ws, const int* __restrict__ iw)
{
  __shared__ float mid[DD][68];
  __shared__ float mp[68];
  __shared__ float w1b[DD*3];
  __shared__ float w2s[ID*3];
  int tid = threadIdx.x;
  int a = blockIdx.x;
  for (int idx=tid; idx<DD*68; idx+=256) (&mid[0][0])[idx] = 0.f;
  if (tid < ID*3) w2s[tid] = c2w[it*ID*3 + tid];
  __syncthreads();
  int nnz = iw[IOFF_CNT + a]; if (nnz > CAP) nnz = CAP;
  for (int q=0; q<nnz; q++){
    int   b = iw[IOFF_CIDX + a*CAP + q];
    float v = ws[OFF_CVAL + a*CAP + q];
    if (tid < 68) mp[tid] = (tid>=1 && tid<=ID) ? ws[OFF_M + b*ID + tid-1] : 0.f;
    if (tid >= 64){                       // threads 64..255 cover the 192 w1 taps
      int r = tid - 64;
      if (r < DD*3){ int o=r/3, k=r%3; w1b[r] = c1w[((it*DD+o)*NN + b)*3 + k]; }
    }
    __syncthreads();
    for (int idx=tid; idx<DD*ID; idx+=256){
      int o = idx/ID, cc = idx%ID;
      float t0 = w1b[o*3]*mp[cc] + w1b[o*3+1]*mp[cc+1] + w1b[o*3+2]*mp[cc+2];
      mid[o][cc] += v*t0;
    }
    __syncthreads();
  }
  for (int idx=tid; idx<DD*ID; idx+=256){ int o=idx/ID, cc=idx%ID; mid[o][cc] += c1b[it*DD+o]; }
  __syncthreads();
  if (tid < DD){
    int x = tid;
    float s = c2b[it];
    for (int cc=0; cc<ID; cc++){
      #pragma unroll
      for (int k=0;k<3;k++){
        int oo = x + k - 1;
        if (oo >= 0 && oo < DD) s += mid[oo][cc]*w2s[cc*3+k];
      }
    }
    ws[OFF_CM + a*132 + ID + x] = s;
  }
}

// ---- B5: gate score + per-mol segment softmax + GRU; one block per mol ----
__global__ __launch_bounds__(256) void k_gru(
    const int* __restrict__ mb,
    const float* __restrict__ lfw, const float* __restrict__ lfb,
    const float* __restrict__ wih, const float* __restrict__ whh,
    const float* __restrict__ bih, const float* __restrict__ bhh,
    float* __restrict__ ws)
{
  __shared__ int memb[MAXM]; __shared__ int lcnt;
  __shared__ float cms [MAXM][132];
  __shared__ float hrow[MAXM][68];
  __shared__ float rz  [MAXM][132];
  __shared__ float hnew[MAXM][68];
  __shared__ float fv[MAXM], av[MAXM];
  int tid = threadIdx.x, m = blockIdx.x;
  if (tid==0) lcnt = 0;
  __syncthreads();
  for (int i=tid; i<NN; i+=256)
    if (mb[i]==m){ int p = atomicAdd(&lcnt,1); if (p<MAXM) memb[p]=i; }
  __syncthreads();
  int M = lcnt; if (M > MAXM) M = MAXM;
  for (int idx=tid; idx<M*130; idx+=256){ int i=idx/130, j=idx%130; cms[i][j]=ws[OFF_CM+memb[i]*132+j]; }
  for (int idx=tid; idx<M*ID;  idx+=256){ int i=idx/ID,  j=idx%ID;  hrow[i][j]=ws[OFF_OUT+memb[i]*ID+j]; }
  __syncthreads();
  if (tid < M){
    float s = lfb[0];
    for (int j=0;j<130;j++) s += cms[tid][j]*lfw[j];
    fv[tid] = (s > 0.f) ? s : 0.01f*s;     // leaky_relu
  }
  __syncthreads();
  if (tid < 64){
    float x = (tid<M) ? fv[tid] : -INFINITY;
    float mx = x;
    for (int o=32;o>0;o>>=1) mx = fmaxf(mx, __shfl_xor(mx,o,64));
    float ex = (tid<M) ? expf(x-mx) : 0.f;
    float sm = ex;
    for (int o=32;o>0;o>>=1) sm += __shfl_xor(sm,o,64);
    if (tid<M) av[tid] = ex/(sm + 1e-16f);
  }
  __syncthreads();
  for (int idx=tid; idx<M*132; idx+=256){   // r,z gates
    int u = idx / M, i = idx % M;
    float d1 = 0.f;
    const float* w1 = wih + u*130;
    for (int j=0;j<130;j++) d1 += cms[i][j]*w1[j];
    float d2 = 0.f;
    const float* w2 = whh + u*ID;
    for (int j=0;j<ID;j++) d2 += hrow[i][j]*w2[j];
    rz[i][u] = sgm(bih[u] + av[i]*d1 + bhh[u] + d2);
  }
  __syncthreads();
  for (int idx=tid; idx<M*ID; idx+=256){    // n gate + blend
    int u = idx / M, i = idx % M;
    int uu = 132 + u;
    float d1 = 0.f;
    const float* w1 = wih + uu*130;
    for (int j=0;j<130;j++) d1 += cms[i][j]*w1[j];
    float inn = bih[uu] + av[i]*d1;
    float hn = bhh[uu];
    const float* w2 = whh + uu*ID;
    for (int j=0;j<ID;j++) hn += hrow[i][j]*w2[j];
    float r = rz[i][u], z = rz[i][66+u];
    float nn_ = tanhf(inn + r*hn);
    hnew[i][u] = (1.f - z)*nn_ + z*hrow[i][u];
  }
  __syncthreads();
  for (int idx=tid; idx<M*ID; idx+=256){ int i=idx/ID, j=idx%ID; ws[OFF_OUT+memb[i]*ID+j] = hnew[i][j]; }
}

// ---- Set2Set readout, one block per mol, 3 internal iterations ----
__global__ __launch_bounds__(256) void k_s2s(
    const int* __restrict__ mb,
    const float* __restrict__ wih, const float* __restrict__ whh,
    const float* __restrict__ bih, const float* __restrict__ bhh,
    float* __restrict__ ws)
{
  __shared__ int memb[MAXM]; __shared__ int lcnt;
  __shared__ float orow[MAXM][68];
  __shared__ float hsv[66], csv[66], qsv[132], gv[264];
  __shared__ float av[MAXM];
  int tid = threadIdx.x, m = blockIdx.x;
  if (tid==0) lcnt = 0;
  __syncthreads();
  for (int i=tid; i<NN; i+=256)
    if (mb[i]==m){ int p = atomicAdd(&lcnt,1); if (p<MAXM) memb[p]=i; }
  __syncthreads();
  int M = lcnt; if (M > MAXM) M = MAXM;
  for (int idx=tid; idx<M*ID; idx+=256){ int i=idx/ID, j=idx%ID; orow[i][j]=ws[OFF_OUT+memb[i]*ID+j]; }
  if (tid < 66){ hsv[tid]=0.f; csv[tid]=0.f; }
  if (tid < 132) qsv[tid]=0.f;
  __syncthreads();
  for (int step=0; step<3; step++){
    for (int u=tid; u<264; u+=256){
      float s = bih[u] + bhh[u];
      const float* w1 = wih + u*132;
      for (int j=0;j<132;j++) s += qsv[j]*w1[j];
      const float* w2 = whh + u*ID;
      for (int j=0;j<ID;j++) s += hsv[j]*w2[j];
      gv[u] = s;
    }
    __syncthreads();
    if (tid < 66){
      float ig=gv[tid], fg=gv[66+tid], gg=gv[132+tid], og=gv[198+tid];
      float c = sgm(fg)*csv[tid] + sgm(ig)*tanhf(gg);
      csv[tid] = c;
      hsv[tid] = sgm(og)*tanhf(c);
    }
    __syncthreads();
    if (tid < 64){
      float e = -INFINITY;
      if (tid < M){ e = 0.f; for (int j=0;j<ID;j++) e += orow[tid][j]*hsv[j]; }
      float mx = e;
      for (int o=32;o>0;o>>=1) mx = fmaxf(mx, __shfl_xor(mx,o,64));
      float ex = (tid<M) ? expf(e-mx) : 0.f;
      float sm = ex;
      for (int o=32;o>0;o>>=1) sm += __shfl_xor(sm,o,64);
      if (tid<M) av[tid] = ex/(sm + 1e-16f);
    }
    __syncthreads();
    if (tid < 66){
      float r = 0.f;
      for (int i=0;i<M;i++) r += av[i]*orow[i][tid];
      qsv[tid]      = hsv[tid];
      qsv[66+tid]   = r;
    }
    __syncthreads();
  }
  if (tid < 132) ws[OFF_QSTAR + m*132 + tid] = qsv[tid];
}

// ---- fingers MLP + concat + final linear; one block per mol ----
__global__ __launch_bounds__(256) void k_final(
    const float* __restrict__ fing,
    const float* __restrict__ d1w, const float* __restrict__ d1b,
    const float* __restrict__ d2w, const float* __restrict__ d2b,
    const float* __restrict__ d3w, const float* __restrict__ d3b,
    const float* __restrict__ pw,  const float* __restrict__ pb,
    const float* __restrict__ ws,  float* __restrict__ outp)
{
  __shared__ __align__(16) float fin[1024];
  __shared__ __align__(16) float f1[512];
  __shared__ __align__(16) float f2[256];
  __shared__ __align__(16) float f3[64];
  int tid = threadIdx.x, b = blockIdx.x;
  for (int j=tid; j<1024; j+=256) fin[j] = fing[b*1024+j];
  __syncthreads();
  {
    int q = tid & 7;
    for (int u = tid>>3; u < 512; u += 32){
      float s = 0.f;
      const float4* w4 = (const float4*)(d1w + u*1024);
      const float4* x4 = (const float4*)fin;
      for (int jj=q; jj<256; jj+=8){ float4 wv=w4[jj], xv=x4[jj]; s += wv.x*xv.x+wv.y*xv.y+wv.z*xv.z+wv.w*xv.w; }
      s += __shfl_xor(s,1,64); s += __shfl_xor(s,2,64); s += __shfl_xor(s,4,64);
      if (q==0) f1[u] = fmaxf(s + d1b[u], 0.f);
    }
  }
  __syncthreads();
  {
    int q = tid & 7;
    for (int u = tid>>3; u < 256; u += 32){
      float s = 0.f;
      const float4* w4 = (const float4*)(d2w + u*512);
      const float4* x4 = (const float4*)f1;
      for (int jj=q; jj<128; jj+=8){ float4 wv=w4[jj], xv=x4[jj]; s += wv.x*xv.x+wv.y*xv.y+wv.z*xv.z+wv.w*xv.w; }
      s += __shfl_xor(s,1,64); s += __shfl_xor(s,2,64); s += __shfl_xor(s,4,64);
      if (q==0) f2[u] = fmaxf(s + d2b[u], 0.f);
    }
  }
  __syncthreads();
  {
    int q = tid & 7;
    for (int u = tid>>3; u < 64; u += 32){
      float s = 0.f;
      const float4* w4 = (const float4*)(d3w + u*256);
      const float4* x4 = (const float4*)f2;
      for (int jj=q; jj<64; jj+=8){ float4 wv=w4[jj], xv=x4[jj]; s += wv.x*xv.x+wv.y*xv.y+wv.z*xv.z+wv.w*xv.w; }
      s += __shfl_xor(s,1,64); s += __shfl_xor(s,2,64); s += __shfl_xor(s,4,64);
      if (q==0) f3[u] = s + d3b[u];
    }
  }
  __syncthreads();
  if (tid < 64){
    float s = 0.f;
    for (int j=tid; j<132; j+=64) s += ws[OFF_QSTAR + b*132 + j]*pw[j];
    s += f3[tid]*pw[132 + tid];
    for (int o=32;o>0;o>>=1) s += __shfl_xor(s,o,64);
    if (tid==0) outp[b] = s + pb[0];
  }
}

extern "C" void kernel_launch(void* const* d_in, const int* in_sizes, int n_in,
                              void* d_out, int out_size, void* d_ws, size_t ws_size,
                              hipStream_t stream)
{
  const float* mnc = (const float*)d_in[0];
  const float* ea  = (const float*)d_in[1];
  const float* fing= (const float*)d_in[2];
  const int*   eidx= (const int*)d_in[3];
  const int*   mb  = (const int*)d_in[4];
  const float* adj = (const float*)d_in[5];
  const float* e1w=(const float*)d_in[6],  *e1b=(const float*)d_in[7];
  const float* e2w=(const float*)d_in[8],  *e2b=(const float*)d_in[9];
  const float* c1w=(const float*)d_in[10], *c1b=(const float*)d_in[11];
  const float* c2w=(const float*)d_in[12], *c2b=(const float*)d_in[13];
  const float* n1w=(const float*)d_in[14], *n1b=(const float*)d_in[15];
  const float* n2w=(const float*)d_in[16], *n2b=(const float*)d_in[17];
  const float* bng=(const float*)d_in[18], *bnb=(const float*)d_in[19];
  const float* nnw=(const float*)d_in[20], *nnb=(const float*)d_in[21];
  const float* root=(const float*)d_in[22],*nnbias=(const float*)d_in[23];
  const float* cv1w=(const float*)d_in[24],*cv1b=(const float*)d_in[25];
  const float* cv2w=(const float*)d_in[26],*cv2b=(const float*)d_in[27];
  const float* lfw=(const float*)d_in[28], *lfb=(const float*)d_in[29];
  const float* gwih=(const float*)d_in[30],*gwhh=(const float*)d_in[31];
  const float* gbih=(const float*)d_in[32],*gbhh=(const float*)d_in[33];
  const float* lwih=(const float*)d_in[34],*lwhh=(const float*)d_in[35];
  const float* lbih=(const float*)d_in[36],*lbhh=(const float*)d_in[37];
  const float* d1w=(const float*)d_in[38], *d1b=(const float*)d_in[39];
  const float* d2w=(const float*)d_in[40], *d2b=(const float*)d_in[41];
  const float* d3w=(const float*)d_in[42], *d3b=(const float*)d_in[43];
  const float* pw =(const float*)d_in[44], *pb =(const float*)d_in[45];
  float* ws = (float*)d_ws;
  int*   iw = (int*)(ws + OFF_FEND);
  float* outp = (float*)d_out;

  k_zero     <<<(OFF_SMIP+255)/256, 256, 0, stream>>>(ws, iw);
  k_edge     <<<EE/EB, 256, 0, stream>>>(mnc, eidx, e1w,e1b, e2w,e2b, c1w,c1b, c2w,c2b, ws);
  k_node     <<<NN/NB, 256, 0, stream>>>(mnc, n1w,n1b, n2w,n2b, ws);
  k_bn_stats <<<ID, 256, 0, stream>>>(ws);
  k_bn_apply <<<(NN*ID+255)/256, 256, 0, stream>>>(bng, bnb, ws);
  k_buildq   <<<(726*ID+255)/256, 256, 0, stream>>>(nnw, nnb, ws);
  k_csc      <<<(NN*NN)/256, 256, 0, stream>>>(adj, ws, iw);
  for (int it=0; it<3; ++it){
    k_zero_magg<<<(NN*ID+255)/256, 256, 0, stream>>>(ws);
    k_msg    <<<EE/MEB, 256, 0, stream>>>(ea, eidx, ws);
    k_mnode  <<<NN/NB, 256, 0, stream>>>(root, nnbias, ws);
    k_spconv <<<NN, 256, 0, stream>>>(cv1w, cv1b, cv2w, cv2b, it, ws, iw);
    k_gru    <<<BB, 256, 0, stream>>>(mb, lfw, lfb, gwih, gwhh, gbih, gbhh, ws);
  }
  k_s2s      <<<BB, 256, 0, stream>>>(mb, lwih, lwhh, lbih, lbhh, ws);
  k_final    <<<BB, 256, 0, stream>>>(fing, d1w,d1b, d2w,d2b, d3w,d3b, pw,pb, ws, outp);
}

// Round 2
// 814.870 us; speedup vs baseline: 1.7819x; 1.7819x over previous
//
#include <hip/hip_runtime.h>
#include <math.h>

// Problem constants (fixed by the reference)
#define NN 1024   // nodes
#define BB 32     // mols
#define EE 8192   // edges
#define DD 64     // DIM
#define ID 66     // IN_DIM
#define FT 63     // feats dim
#define CAP 128   // max nnz per adj column (data: <=32, same-batch only)
#define MAXM 64   // max nodes per mol (s2s)
#define GM 40     // max nodes per mol (gru kernel, data: 32)

// ---- workspace layout (float offsets) ----
enum : int {
  OFF_ACC   = 0,                       // N*4   coor segsum accumulator
  OFF_MI    = OFF_ACC + NN*4,          // N*64  m_i accumulator (63 used)
  OFF_DEG   = OFF_MI + NN*64,          // N     degree (float)
  OFF_SMIP  = OFF_DEG + NN,            // N*66  pre-BN smi
  OFF_OUT   = OFF_SMIP + NN*ID,        // N*66  h == out
  OFF_STATS = OFF_OUT + NN*ID,         // 144   mean[66], rstd[66]
  OFF_Q     = OFF_STATS + 144,         // 726*66 augmented NNConv weight [k][o]
  OFF_MAGG  = OFF_Q + 47920,           // N*66  per-iter message aggregate
  OFF_M     = OFF_MAGG + NN*ID,        // N*66  m buffer
  OFF_CM    = OFF_M + NN*ID,           // N*132 cm = [m(66), sp(64)] stride 132
  OFF_QSTAR = OFF_CM + NN*132,         // 32*132
  OFF_CVAL  = OFF_QSTAR + BB*132,      // N*CAP csc values
  OFF_W1P   = OFF_CVAL + NN*CAP,       // 256*128 padded e1w
  OFF_W2P   = OFF_W1P + 256*128,       // 64*256  padded e2w
  OFF_C1P   = OFF_W2P + 64*256,        // 256*64  padded c1w
  OFF_GIH   = OFF_C1P + 256*64,        // 198*132 padded gru_w_ih
  OFF_GHH   = OFF_GIH + 198*132,       // 198*68  padded gru_w_hh
  OFF_F1    = OFF_GHH + 198*68,        // 32*512
  OFF_F2    = OFF_F1 + BB*512,         // 32*256
  OFF_FEND  = OFF_F2 + BB*256
};
enum : int {  // int region, starts at ws + OFF_FEND
  IOFF_CNT  = 0,        // N
  IOFF_CIDX = NN,       // N*CAP
  IOFF_END  = NN + NN*CAP
};

__device__ __forceinline__ float sgm(float x){ return 1.0f/(1.0f+expf(-x)); }
__device__ __forceinline__ float silu_(float x){ return x/(1.0f+expf(-x)); }
__device__ __forceinline__ float nan0(float v){ return (v!=v) ? 0.0f : v; }
__device__ __forceinline__ float hsum4(float4 v){ return v.x+v.y+v.z+v.w; }
#define FMA4(A,X,W) {A.x += (X).x*(W).x; A.y += (X).y*(W).y; A.z += (X).z*(W).z; A.w += (X).w*(W).w;}
#define Z4 {0.f,0.f,0.f,0.f}

// ---- zero accumulators ----
__global__ void k_zero(float* __restrict__ ws, int* __restrict__ iw){
  int i = blockIdx.x*256 + threadIdx.x;
  if (i < OFF_SMIP) ws[i] = 0.f;          // ACC, MI, DEG contiguous
  if (i < NN) iw[IOFF_CNT + i] = 0;
}

// ---- pad weight copies for float4 dots ----
__global__ void k_prep(const float* __restrict__ e1w, const float* __restrict__ e2w,
                       const float* __restrict__ c1w,
                       const float* __restrict__ gwih, const float* __restrict__ gwhh,
                       float* __restrict__ ws){
  int idx = blockIdx.x*256 + threadIdx.x;
  if (idx < 32768){ int u=idx>>7, j=idx&127; ws[OFF_W1P+idx] = (u<254 && j<127)? e1w[u*127+j] : 0.f; }
  int i2 = idx - 32768;
  if (i2 >= 0 && i2 < 16384){ int u=i2>>8, j=i2&255; ws[OFF_W2P+i2] = (u<63 && j<254)? e2w[u*254+j] : 0.f; }
  int i3 = idx - 49152;
  if (i3 >= 0 && i3 < 16384){ int u=i3>>6, j=i3&63; ws[OFF_C1P+i3] = (u<252 && j<63)? c1w[u*63+j] : 0.f; }
  int i4 = idx - 65536;
  if (i4 >= 0 && i4 < 198*132){ int u=i4/132, j=i4%132; ws[OFF_GIH+i4] = (j<130)? gwih[u*130+j] : 0.f; }
  int i5 = idx - (65536 + 198*132);
  if (i5 >= 0 && i5 < 198*68){ int u=i5/68, j=i5%68; ws[OFF_GHH+i5] = (j<66)? gwhh[u*66+j] : 0.f; }
}

// ---- A1: per-edge EGNN MLP chain, float4 register-tiled ----
#define EB 16
__global__ __launch_bounds__(256) void k_edge(
    const float* __restrict__ mnc, const int* __restrict__ eidx,
    const float* __restrict__ e1b, const float* __restrict__ e2b,
    const float* __restrict__ c1b,
    const float* __restrict__ c2w, const float* __restrict__ c2b,
    float* __restrict__ ws)
{
  __shared__ float xin[EB][132];   // 0..126 data, 127 zero-pad
  __shared__ float eh [EB][256];   // 254 used, 254..255 pad; later reused as ch (252)
  __shared__ float mij[EB][64];    // 63 used, 63 pad
  __shared__ int   ssrc[EB], sdst[EB];
  __shared__ float srel[EB][4];
  int tid = threadIdx.x;
  int e0b = blockIdx.x*EB;
  if (tid < EB){
    int e = e0b + tid;
    int s = eidx[e], d = eidx[EE + e];
    ssrc[tid]=s; sdst[tid]=d;
    float rd = 0.f;
    #pragma unroll
    for (int k=0;k<3;k++){ float r = mnc[s*ID+k]-mnc[d*ID+k]; srel[tid][k]=r; rd += r*r; }
    xin[tid][126] = rd; xin[tid][127] = 0.f;
    mij[tid][63]  = 0.f;
  }
  if (tid < EB*2){ eh[tid>>1][254+(tid&1)] = 0.f; }
  __syncthreads();
  for (int idx=tid; idx<EB*126; idx+=256){
    int e = idx/126, j = idx%126;
    int node = (j < FT) ? sdst[e] : ssrc[e];
    int jj   = (j < FT) ? j : (j-FT);
    xin[e][j] = mnc[node*ID + 3 + jj];
  }
  __syncthreads();
  // L1: eh = silu(xin @ W1P^T + e1b)   K=128, U=254(pad 256)
  {
    int eg = tid&7, e0 = eg*2, ug = tid>>3;
    const float4* xa = (const float4*)&xin[e0][0];
    const float4* xb = (const float4*)&xin[e0+1][0];
    for (int u0 = ug*4; u0 < 256; u0 += 128){
      const float4* w0 = (const float4*)(ws+OFF_W1P+(u0+0)*128);
      const float4* w1 = (const float4*)(ws+OFF_W1P+(u0+1)*128);
      const float4* w2 = (const float4*)(ws+OFF_W1P+(u0+2)*128);
      const float4* w3 = (const float4*)(ws+OFF_W1P+(u0+3)*128);
      float4 a0=Z4,a1=Z4,a2=Z4,a3=Z4,b0=Z4,b1=Z4,b2=Z4,b3=Z4;
      for (int jj=0;jj<32;jj++){
        float4 xva=xa[jj], xvb=xb[jj];
        float4 wv0=w0[jj],wv1=w1[jj],wv2=w2[jj],wv3=w3[jj];
        FMA4(a0,xva,wv0) FMA4(a1,xva,wv1) FMA4(a2,xva,wv2) FMA4(a3,xva,wv3)
        FMA4(b0,xvb,wv0) FMA4(b1,xvb,wv1) FMA4(b2,xvb,wv2) FMA4(b3,xvb,wv3)
      }
      float ha[4] = {hsum4(a0),hsum4(a1),hsum4(a2),hsum4(a3)};
      float hb[4] = {hsum4(b0),hsum4(b1),hsum4(b2),hsum4(b3)};
      #pragma unroll
      for (int ui=0;ui<4;ui++){
        int u = u0+ui;
        if (u < 254){
          float bv = e1b[u];
          eh[e0  ][u] = silu_(bv + ha[ui]);
          eh[e0+1][u] = silu_(bv + hb[ui]);
        }
      }
    }
  }
  __syncthreads();
  // L2: mij = silu(eh @ W2P^T + e2b)   K=256, U=63(pad 64)
  {
    int eg = tid&7, e0 = eg*2, ug = tid>>3;
    int u0 = ug*2;
    const float4* xa = (const float4*)&eh[e0][0];
    const float4* xb = (const float4*)&eh[e0+1][0];
    const float4* w0 = (const float4*)(ws+OFF_W2P+(u0+0)*256);
    const float4* w1 = (const float4*)(ws+OFF_W2P+(u0+1)*256);
    float4 a0=Z4,a1=Z4,b0=Z4,b1=Z4;
    for (int jj=0;jj<64;jj++){
      float4 xva=xa[jj], xvb=xb[jj];
      float4 wv0=w0[jj], wv1=w1[jj];
      FMA4(a0,xva,wv0) FMA4(a1,xva,wv1)
      FMA4(b0,xvb,wv0) FMA4(b1,xvb,wv1)
    }
    float ha[2]={hsum4(a0),hsum4(a1)}, hb[2]={hsum4(b0),hsum4(b1)};
    #pragma unroll
    for (int ui=0;ui<2;ui++){
      int u = u0+ui;
      if (u < 63){
        float bv = e2b[u];
        mij[e0  ][u] = silu_(bv + ha[ui]);
        mij[e0+1][u] = silu_(bv + hb[ui]);
      }
    }
  }
  __syncthreads();
  // scatter m_i and degree
  for (int idx=tid; idx<EB*FT; idx+=256){
    int e = idx/FT, u = idx%FT;
    atomicAdd(ws + OFF_MI + sdst[e]*64 + u, mij[e][u]);
  }
  if (tid < EB) atomicAdd(ws + OFF_DEG + sdst[tid], 1.0f);
  __syncthreads();
  // L3: ch = silu(mij @ C1P^T + c1b)  K=64, U=252 -> stored into eh
  {
    int eg = tid&7, e0 = eg*2, ug = tid>>3;
    const float4* xa = (const float4*)&mij[e0][0];
    const float4* xb = (const float4*)&mij[e0+1][0];
    for (int u0 = ug*4; u0 < 256; u0 += 128){
      const float4* w0 = (const float4*)(ws+OFF_C1P+(u0+0)*64);
      const float4* w1 = (const float4*)(ws+OFF_C1P+(u0+1)*64);
      const float4* w2 = (const float4*)(ws+OFF_C1P+(u0+2)*64);
      const float4* w3 = (const float4*)(ws+OFF_C1P+(u0+3)*64);
      float4 a0=Z4,a1=Z4,a2=Z4,a3=Z4,b0=Z4,b1=Z4,b2=Z4,b3=Z4;
      for (int jj=0;jj<16;jj++){
        float4 xva=xa[jj], xvb=xb[jj];
        float4 wv0=w0[jj],wv1=w1[jj],wv2=w2[jj],wv3=w3[jj];
        FMA4(a0,xva,wv0) FMA4(a1,xva,wv1) FMA4(a2,xva,wv2) FMA4(a3,xva,wv3)
        FMA4(b0,xvb,wv0) FMA4(b1,xvb,wv1) FMA4(b2,xvb,wv2) FMA4(b3,xvb,wv3)
      }
      float ha[4] = {hsum4(a0),hsum4(a1),hsum4(a2),hsum4(a3)};
      float hb[4] = {hsum4(b0),hsum4(b1),hsum4(b2),hsum4(b3)};
      #pragma unroll
      for (int ui=0;ui<4;ui++){
        int u = u0+ui;
        if (u < 252){
          float bv = c1b[u];
          eh[e0  ][u] = silu_(bv + ha[ui]);
          eh[e0+1][u] = silu_(bv + hb[ui]);
        }
      }
    }
  }
  __syncthreads();
  // L4: cw scalar (dot 252) + coor scatter
  if (tid < EB*4){
    int e = tid >> 2, q = tid & 3;
    const float4* xr = (const float4*)&eh[e][0];
    const float4* wr = (const float4*)c2w;
    float4 a = Z4;
    for (int jj=q; jj<63; jj+=4){ float4 xv=xr[jj], wv=wr[jj]; FMA4(a,xv,wv) }
    float s = hsum4(a);
    s += __shfl_down(s, 1, 64);
    s += __shfl_down(s, 2, 64);
    if (q == 0){
      float cw = s + c2b[0];
      #pragma unroll
      for (int k=0;k<3;k++) atomicAdd(ws + OFF_ACC + sdst[e]*4 + k, cw*srel[e][k]);
    }
  }
}

// ---- A2: node MLP -> smi_pre ----
#define NB 16
__global__ __launch_bounds__(256) void k_node(
    const float* __restrict__ mnc,
    const float* __restrict__ n1w, const float* __restrict__ n1b,
    const float* __restrict__ n2w, const float* __restrict__ n2b,
    float* __restrict__ ws)
{
  __shared__ float xin[NB][132];  // 126 used
  __shared__ float t1 [NB][132];
  int tid = threadIdx.x;
  int n0 = blockIdx.x*NB;
  for (int idx=tid; idx<NB*126; idx+=256){
    int e = idx/126, j = idx%126;
    int node = n0 + e;
    xin[e][j] = (j < FT) ? mnc[node*ID + 3 + j] : ws[OFF_MI + node*64 + (j-FT)];
  }
  __syncthreads();
  for (int idx=tid; idx<NB*126; idx+=256){
    int e = idx & 15, u = idx >> 4;
    float s = n1b[u];
    const float* w = n1w + u*126;
    for (int j=0;j<126;j++) s += xin[e][j]*w[j];
    t1[e][u] = silu_(s);
  }
  __syncthreads();
  for (int idx=tid; idx<NB*FT; idx+=256){
    int e = idx & 15, u = idx >> 4;
    float s = n2b[u];
    const float* w = n2w + u*126;
    for (int j=0;j<126;j++) s += t1[e][j]*w[j];
    int node = n0 + e;
    ws[OFF_SMIP + node*ID + 3 + u] = nan0(xin[e][u] + s);
  }
  if (tid < NB*3){
    int e = tid/3, k = tid%3;
    int node = n0 + e;
    ws[OFF_SMIP + node*ID + k] = nan0(mnc[node*ID + k] + ws[OFF_ACC + node*4 + k]);
  }
}

// ---- A3: batchnorm ----
__global__ __launch_bounds__(256) void k_bn_stats(float* __restrict__ ws){
  __shared__ float scr[8];
  int j = blockIdx.x, tid = threadIdx.x;
  float s=0.f, ss=0.f;
  for (int i=tid; i<NN; i+=256){ float x = ws[OFF_SMIP + i*ID + j]; s+=x; ss+=x*x; }
  for (int o=32;o>0;o>>=1){ s += __shfl_down(s,o,64); ss += __shfl_down(ss,o,64); }
  int w = tid>>6;
  if ((tid&63)==0){ scr[w]=s; scr[4+w]=ss; }
  __syncthreads();
  if (tid==0){
    float S=0,SS=0;
    for (int q=0;q<4;q++){S+=scr[q];SS+=scr[4+q];}
    float mean = S/NN;
    float var  = SS/NN - mean*mean;
    ws[OFF_STATS + j]      = mean;
    ws[OFF_STATS + 66 + j] = 1.0f/sqrtf(var + 1e-5f);
  }
}
__global__ void k_bn_apply(const float* __restrict__ bng, const float* __restrict__ bnb,
                           float* __restrict__ ws){
  int idx = blockIdx.x*256 + threadIdx.x;
  if (idx < NN*ID){
    int j = idx % ID;
    ws[OFF_OUT + idx] = bng[j]*(ws[OFF_SMIP+idx]-ws[OFF_STATS+j])*ws[OFF_STATS+66+j] + bnb[j];
  }
}

// ---- augmented NNConv weight Q[(i*11+t), o] ----
__global__ void k_buildq(const float* __restrict__ nnw, const float* __restrict__ nnb,
                         float* __restrict__ ws){
  int idx = blockIdx.x*256 + threadIdx.x;
  if (idx < 726*ID){
    int k = idx/ID, o = idx%ID;
    int i = k/11, t = k%11;
    ws[OFF_Q + idx] = (t<10) ? nnw[(i*ID+o)*10 + t] : nnb[i*ID+o];
  }
}

// ---- CSC of adj ----
__global__ void k_csc(const float* __restrict__ adj, float* __restrict__ ws, int* __restrict__ iw){
  int idx = blockIdx.x*256 + threadIdx.x;
  if (idx < NN*NN){
    float v = adj[idx];
    if (v != 0.0f){
      int a = idx % NN, b = idx / NN;
      int p = atomicAdd(iw + IOFF_CNT + a, 1);
      if (p < CAP){ iw[IOFF_CIDX + a*CAP + p] = b; ws[OFF_CVAL + a*CAP + p] = v; }
    }
  }
}

__global__ void k_zero_magg(float* __restrict__ ws){
  int i = blockIdx.x*256 + threadIdx.x;
  if (i < NN*ID) ws[OFF_MAGG + i] = 0.f;
}

// ---- B1+B2: msg = P @ Q with P chunk precomputed in LDS; scatter into MAGG ----
#define MEB 16
__global__ __launch_bounds__(256) void k_msg(
    const float* __restrict__ ea, const int* __restrict__ eidx, float* __restrict__ ws)
{
  __shared__ float xs [MEB][68];
  __shared__ float eas[MEB][12];
  __shared__ float Pc [MEB][68];
  __shared__ float qct[66][68];    // Q^T chunk: [o][kk], pads kk 66..67
  __shared__ int ssrc[MEB], sdst[MEB];
  int tid = threadIdx.x;
  int e0b = blockIdx.x*MEB;
  if (tid < MEB){
    ssrc[tid]=eidx[e0b+tid]; sdst[tid]=eidx[EE+e0b+tid];
    xs[tid][66]=0.f; xs[tid][67]=0.f; Pc[tid][66]=0.f; Pc[tid][67]=0.f;
  }
  if (tid < 66){ qct[tid][66]=0.f; qct[tid][67]=0.f; }
  __syncthreads();
  for (int idx=tid; idx<MEB*ID; idx+=256){ int e=idx/ID, i=idx%ID; xs[e][i]=ws[OFF_OUT+ssrc[e]*ID+i]; }
  for (int idx=tid; idx<MEB*11; idx+=256){ int e=idx/11, t=idx%11; eas[e][t] = (t<10)? ea[(e0b+e)*10+t] : 1.0f; }
  __syncthreads();
  int og = tid>>2, eg = tid&3, ee0 = eg*4;
  float macc[2][4] = {{0.f,0.f,0.f,0.f},{0.f,0.f,0.f,0.f}};
  for (int c=0;c<11;c++){
    for (int idx=tid; idx<66*66; idx+=256){
      int kk=idx/66, o=idx%66;
      qct[o][kk] = ws[OFF_Q + (c*66+kk)*ID + o];
    }
    for (int idx=tid; idx<MEB*66; idx+=256){
      int e=idx/66, kk=idx%66; int kg = c*66+kk;
      Pc[e][kk] = xs[e][kg/11]*eas[e][kg%11];
    }
    __syncthreads();
    const float4* p0 = (const float4*)&Pc[ee0+0][0];
    const float4* p1 = (const float4*)&Pc[ee0+1][0];
    const float4* p2 = (const float4*)&Pc[ee0+2][0];
    const float4* p3 = (const float4*)&Pc[ee0+3][0];
    int np=0;
    for (int o=og; o<66; o+=64, np++){
      const float4* qr = (const float4*)&qct[o][0];
      float4 a0=Z4,a1=Z4,a2=Z4,a3=Z4;
      for (int jj=0;jj<17;jj++){
        float4 q4=qr[jj];
        float4 b0=p0[jj],b1=p1[jj],b2=p2[jj],b3=p3[jj];
        FMA4(a0,b0,q4) FMA4(a1,b1,q4) FMA4(a2,b2,q4) FMA4(a3,b3,q4)
      }
      macc[np][0]+=hsum4(a0); macc[np][1]+=hsum4(a1); macc[np][2]+=hsum4(a2); macc[np][3]+=hsum4(a3);
    }
    __syncthreads();
  }
  int np=0;
  for (int o=og; o<66; o+=64, np++){
    #pragma unroll
    for (int ii=0;ii<4;ii++) atomicAdd(ws + OFF_MAGG + sdst[ee0+ii]*ID + o, macc[np][ii]);
  }
}

// ---- B3: m = relu(magg/deg + out@root + nn_bias) ----
__global__ __launch_bounds__(256) void k_mnode(
    const float* __restrict__ root, const float* __restrict__ nnbias, float* __restrict__ ws)
{
  __shared__ float rs[66][68];
  __shared__ float xo[NB][68];
  int tid = threadIdx.x;
  int n0 = blockIdx.x*NB;
  for (int idx=tid; idx<66*ID; idx+=256){ int j=idx/ID, o=idx%ID; rs[j][o]=root[idx]; }
  for (int idx=tid; idx<NB*ID; idx+=256){ int e=idx/ID, j=idx%ID; xo[e][j]=ws[OFF_OUT+(n0+e)*ID+j]; }
  __syncthreads();
  for (int idx=tid; idx<NB*ID; idx+=256){
    int e = idx & 15, o = idx >> 4;
    int node = n0 + e;
    float s = nnbias[o] + ws[OFF_MAGG + node*ID + o] / fmaxf(ws[OFF_DEG + node], 1.0f);
    for (int j=0;j<ID;j++) s += xo[e][j]*rs[j][o];
    s = fmaxf(s, 0.0f);
    ws[OFF_M  + node*ID + o] = s;
    ws[OFF_CM + node*132 + o] = s;
  }
}

// ---- B4: fused sparse conv, one block per node ----
__global__ __launch_bounds__(256) void k_spconv(
    const float* __restrict__ c1w, const float* __restrict__ c1b,
    const float* __restrict__ c2w, const float* __restrict__ c2b,
    int it, float* __restrict__ ws, const int* __restrict__ iw)
{
  __shared__ float mid[DD][68];
  __shared__ float mp[68];
  __shared__ float w1b[DD*3];
  __shared__ float w2s[ID*3];
  int tid = threadIdx.x;
  int a = blockIdx.x;
  for (int idx=tid; idx<DD*68; idx+=256) (&mid[0][0])[idx] = 0.f;
  if (tid < ID*3) w2s[tid] = c2w[it*ID*3 + tid];
  __syncthreads();
  int nnz = iw[IOFF_CNT + a]; if (nnz > CAP) nnz = CAP;
  for (int q=0; q<nnz; q++){
    int   b = iw[IOFF_CIDX + a*CAP + q];
    float v = ws[OFF_CVAL + a*CAP + q];
    if (tid < 68) mp[tid] = (tid>=1 && tid<=ID) ? ws[OFF_M + b*ID + tid-1] : 0.f;
    if (tid >= 64){
      int r = tid - 64;
      if (r < DD*3){ int o=r/3, k=r%3; w1b[r] = c1w[((it*DD+o)*NN + b)*3 + k]; }
    }
    __syncthreads();
    for (int idx=tid; idx<DD*ID; idx+=256){
      int o = idx/ID, cc = idx%ID;
      float t0 = w1b[o*3]*mp[cc] + w1b[o*3+1]*mp[cc+1] + w1b[o*3+2]*mp[cc+2];
      mid[o][cc] += v*t0;
    }
    __syncthreads();
  }
  for (int idx=tid; idx<DD*ID; idx+=256){ int o=idx/ID, cc=idx%ID; mid[o][cc] += c1b[it*DD+o]; }
  __syncthreads();
  if (tid < DD){
    int x = tid;
    float s = c2b[it];
    for (int cc=0; cc<ID; cc++){
      #pragma unroll
      for (int k=0;k<3;k++){
        int oo = x + k - 1;
        if (oo >= 0 && oo < DD) s += mid[oo][cc]*w2s[cc*3+k];
      }
    }
    ws[OFF_CM + a*132 + ID + x] = s;
  }
}

// ---- B5: gate + segment softmax + GRU (float4 gate GEMM) ----
__global__ __launch_bounds__(256) void k_gru(
    const int* __restrict__ mb,
    const float* __restrict__ lfw, const float* __restrict__ lfb,
    const float* __restrict__ bih, const float* __restrict__ bhh,
    float* __restrict__ ws)
{
  __shared__ int memb[GM]; __shared__ int lcnt;
  __shared__ float cms [GM][132];
  __shared__ float hrow[GM][68];
  __shared__ float gg  [GM][132];
  __shared__ float gn1 [GM][68];
  __shared__ float gn2 [GM][68];
  __shared__ float av[GM];
  int tid = threadIdx.x, m = blockIdx.x;
  if (tid==0) lcnt = 0;
  __syncthreads();
  for (int i=tid; i<NN; i+=256)
    if (mb[i]==m){ int p = atomicAdd(&lcnt,1); if (p<GM) memb[p]=i; }
  __syncthreads();
  int M = lcnt; if (M > GM) M = GM;
  for (int idx=tid; idx<M*132; idx+=256){ int i=idx/132, j=idx%132; cms[i][j] = (j<130)? ws[OFF_CM+memb[i]*132+j] : 0.f; }
  for (int idx=tid; idx<M*68; idx+=256){ int i=idx/68, j=idx%68; hrow[i][j] = (j<66)? ws[OFF_OUT+memb[i]*ID+j] : 0.f; }
  __syncthreads();
  if (tid < 64){
    float x = -INFINITY;
    if (tid < M){
      float s = lfb[0];
      for (int j=0;j<130;j++) s += cms[tid][j]*lfw[j];
      x = (s > 0.f) ? s : 0.01f*s;
    }
    float mx = x;
    for (int o=32;o>0;o>>=1) mx = fmaxf(mx, __shfl_xor(mx,o,64));
    float ex = (tid<M) ? expf(x-mx) : 0.f;
    float sm = ex;
    for (int o=32;o>0;o>>=1) sm += __shfl_xor(sm,o,64);
    if (tid<M) av[tid] = ex/(sm + 1e-16f);
  }
  __syncthreads();
  {
    int ug = tid>>3, ig = tid&7;
    for (int u=ug; u<198; u+=32){
      const float4* w1 = (const float4*)(ws+OFF_GIH + u*132);
      const float4* w2 = (const float4*)(ws+OFF_GHH + u*68);
      float bv1 = bih[u], bv2 = bhh[u];
      for (int i0 = ig*4; i0 < M; i0 += 32){
        const float4* x0 = (const float4*)&cms[i0+0][0];
        const float4* x1 = (const float4*)&cms[i0+1][0];
        const float4* x2 = (const float4*)&cms[i0+2][0];
        const float4* x3 = (const float4*)&cms[i0+3][0];
        float4 a0=Z4,a1=Z4,a2=Z4,a3=Z4;
        for (int jj=0;jj<33;jj++){
          float4 w=w1[jj];
          FMA4(a0,x0[jj],w) FMA4(a1,x1[jj],w) FMA4(a2,x2[jj],w) FMA4(a3,x3[jj],w)
        }
        const float4* h0 = (const float4*)&hrow[i0+0][0];
        const float4* h1 = (const float4*)&hrow[i0+1][0];
        const float4* h2 = (const float4*)&hrow[i0+2][0];
        const float4* h3 = (const float4*)&hrow[i0+3][0];
        float4 b0=Z4,b1=Z4,b2=Z4,b3=Z4;
        for (int jj=0;jj<17;jj++){
          float4 w=w2[jj];
          FMA4(b0,h0[jj],w) FMA4(b1,h1[jj],w) FMA4(b2,h2[jj],w) FMA4(b3,h3[jj],w)
        }
        float d1[4] = {hsum4(a0),hsum4(a1),hsum4(a2),hsum4(a3)};
        float d2[4] = {hsum4(b0),hsum4(b1),hsum4(b2),hsum4(b3)};
        #pragma unroll
        for (int ii=0;ii<4;ii++){
          int i = i0+ii;
          if (i < M){
            float v1 = bv1 + av[i]*d1[ii];
            float v2 = bv2 + d2[ii];
            if (u < 132) gg[i][u] = sgm(v1+v2);
            else { gn1[i][u-132] = v1; gn2[i][u-132] = v2; }
          }
        }
      }
    }
  }
  __syncthreads();
  for (int idx=tid; idx<M*ID; idx+=256){
    int i = idx/ID, u = idx%ID;
    float r = gg[i][u], z = gg[i][66+u];
    float n_ = tanhf(gn1[i][u] + r*gn2[i][u]);
    ws[OFF_OUT + memb[i]*ID + u] = (1.f - z)*n_ + z*hrow[i][u];
  }
}

// ---- Set2Set readout ----
__global__ __launch_bounds__(256) void k_s2s(
    const int* __restrict__ mb,
    const float* __restrict__ wih, const float* __restrict__ whh,
    const float* __restrict__ bih, const float* __restrict__ bhh,
    float* __restrict__ ws)
{
  __shared__ int memb[MAXM]; __shared__ int lcnt;
  __shared__ float orow[MAXM][68];
  __shared__ float hsv[66], csv[66], qsv[132], gv[264];
  __shared__ float av[MAXM];
  int tid = threadIdx.x, m = blockIdx.x;
  if (tid==0) lcnt = 0;
  __syncthreads();
  for (int i=tid; i<NN; i+=256)
    if (mb[i]==m){ int p = atomicAdd(&lcnt,1); if (p<MAXM) memb[p]=i; }
  __syncthreads();
  int M = lcnt; if (M > MAXM) M = MAXM;
  for (int idx=tid; idx<M*ID; idx+=256){ int i=idx/ID, j=idx%ID; orow[i][j]=ws[OFF_OUT+memb[i]*ID+j]; }
  if (tid < 66){ hsv[tid]=0.f; csv[tid]=0.f; }
  if (tid < 132) qsv[tid]=0.f;
  __syncthreads();
  for (int step=0; step<3; step++){
    for (int u=tid; u<264; u+=256){
      float s = bih[u] + bhh[u];
      const float* w1 = wih + u*132;
      for (int j=0;j<132;j++) s += qsv[j]*w1[j];
      const float* w2 = whh + u*ID;
      for (int j=0;j<ID;j++) s += hsv[j]*w2[j];
      gv[u] = s;
    }
    __syncthreads();
    if (tid < 66){
      float ig=gv[tid], fg=gv[66+tid], gg_=gv[132+tid], og=gv[198+tid];
      float c = sgm(fg)*csv[tid] + sgm(ig)*tanhf(gg_);
      csv[tid] = c;
      hsv[tid] = sgm(og)*tanhf(c);
    }
    __syncthreads();
    if (tid < 64){
      float e = -INFINITY;
      if (tid < M){ e = 0.f; for (int j=0;j<ID;j++) e += orow[tid][j]*hsv[j]; }
      float mx = e;
      for (int o=32;o>0;o>>=1) mx = fmaxf(mx, __shfl_xor(mx,o,64));
      float ex = (tid<M) ? expf(e-mx) : 0.f;
      float sm = ex;
      for (int o=32;o>0;o>>=1) sm += __shfl_xor(sm,o,64);
      if (tid<M) av[tid] = ex/(sm + 1e-16f);
    }
    __syncthreads();
    if (tid < 66){
      float r = 0.f;
      for (int i=0;i<M;i++) r += av[i]*orow[i][tid];
      qsv[tid]      = hsv[tid];
      qsv[66+tid]   = r;
    }
    __syncthreads();
  }
  if (tid < 132) ws[OFF_QSTAR + m*132 + tid] = qsv[tid];
}

// ---- fingers MLP, parallelized: 3 kernels ----
__global__ __launch_bounds__(256) void k_fd1(
    const float* __restrict__ fing, const float* __restrict__ d1w, const float* __restrict__ d1b,
    float* __restrict__ ws)
{
  __shared__ __align__(16) float fin[1024];
  int tid = threadIdx.x;
  int b = blockIdx.x >> 4, u0 = (blockIdx.x & 15)*32;
  for (int j=tid; j<1024; j+=256) fin[j] = fing[b*1024+j];
  __syncthreads();
  int u = u0 + (tid>>3), q = tid & 7;
  const float4* w4 = (const float4*)(d1w + u*1024);
  const float4* x4 = (const float4*)fin;
  float4 a = Z4;
  for (int jj=q; jj<256; jj+=8){ float4 wv=w4[jj], xv=x4[jj]; FMA4(a,xv,wv) }
  float s = hsum4(a);
  s += __shfl_xor(s,1,64); s += __shfl_xor(s,2,64); s += __shfl_xor(s,4,64);
  if (q==0) ws[OFF_F1 + b*512 + u] = fmaxf(s + d1b[u], 0.f);
}
__global__ __launch_bounds__(256) void k_fd2(
    const float* __restrict__ d2w, const float* __restrict__ d2b, float* __restrict__ ws)
{
  __shared__ __align__(16) float f1[512];
  int tid = threadIdx.x;
  int b = blockIdx.x >> 3, u0 = (blockIdx.x & 7)*32;
  for (int j=tid; j<512; j+=256) f1[j] = ws[OFF_F1 + b*512 + j];
  __syncthreads();
  int u = u0 + (tid>>3), q = tid & 7;
  const float4* w4 = (const float4*)(d2w + u*512);
  const float4* x4 = (const float4*)f1;
  float4 a = Z4;
  for (int jj=q; jj<128; jj+=8){ float4 wv=w4[jj], xv=x4[jj]; FMA4(a,xv,wv) }
  float s = hsum4(a);
  s += __shfl_xor(s,1,64); s += __shfl_xor(s,2,64); s += __shfl_xor(s,4,64);
  if (q==0) ws[OFF_F2 + b*256 + u] = fmaxf(s + d2b[u], 0.f);
}
__global__ __launch_bounds__(256) void k_fd3p(
    const float* __restrict__ d3w, const float* __restrict__ d3b,
    const float* __restrict__ pw,  const float* __restrict__ pb,
    const float* __restrict__ ws,  float* __restrict__ outp)
{
  __shared__ __align__(16) float f2[256];
  __shared__ float f3[64];
  int tid = threadIdx.x, b = blockIdx.x;
  for (int j=tid; j<256; j+=256) f2[j] = ws[OFF_F2 + b*256 + j];
  __syncthreads();
  {
    int u = tid>>2, q = tid&3;
    const float4* w4 = (const float4*)(d3w + u*256);
    const float4* x4 = (const float4*)f2;
    float4 a = Z4;
    for (int jj=q; jj<64; jj+=4){ float4 wv=w4[jj], xv=x4[jj]; FMA4(a,xv,wv) }
    float s = hsum4(a);
    s += __shfl_xor(s,1,64); s += __shfl_xor(s,2,64);
    if (q==0) f3[u] = s + d3b[u];
  }
  __syncthreads();
  if (tid < 64){
    float s = 0.f;
    for (int j=tid; j<132; j+=64) s += ws[OFF_QSTAR + b*132 + j]*pw[j];
    s += f3[tid]*pw[132 + tid];
    for (int o=32;o>0;o>>=1) s += __shfl_xor(s,o,64);
    if (tid==0) outp[b] = s + pb[0];
  }
}

extern "C" void kernel_launch(void* const* d_in, const int* in_sizes, int n_in,
                              void* d_out, int out_size, void* d_ws, size_t ws_size,
                              hipStream_t stream)
{
  const float* mnc = (const float*)d_in[0];
  const float* ea  = (const float*)d_in[1];
  const float* fing= (const float*)d_in[2];
  const int*   eidx= (const int*)d_in[3];
  const int*   mb  = (const int*)d_in[4];
  const float* adj = (const float*)d_in[5];
  const float* e1w=(const float*)d_in[6],  *e1b=(const float*)d_in[7];
  const float* e2w=(const float*)d_in[8],  *e2b=(const float*)d_in[9];
  const float* c1w=(const float*)d_in[10], *c1b=(const float*)d_in[11];
  const float* c2w=(const float*)d_in[12], *c2b=(const float*)d_in[13];
  const float* n1w=(const float*)d_in[14], *n1b=(const float*)d_in[15];
  const float* n2w=(const float*)d_in[16], *n2b=(const float*)d_in[17];
  const float* bng=(const float*)d_in[18], *bnb=(const float*)d_in[19];
  const float* nnw=(const float*)d_in[20], *nnb=(const float*)d_in[21];
  const float* root=(const float*)d_in[22],*nnbias=(const float*)d_in[23];
  const float* cv1w=(const float*)d_in[24],*cv1b=(const float*)d_in[25];
  const float* cv2w=(const float*)d_in[26],*cv2b=(const float*)d_in[27];
  const float* lfw=(const float*)d_in[28], *lfb=(const float*)d_in[29];
  const float* gwih=(const float*)d_in[30],*gwhh=(const float*)d_in[31];
  const float* gbih=(const float*)d_in[32],*gbhh=(const float*)d_in[33];
  const float* lwih=(const float*)d_in[34],*lwhh=(const float*)d_in[35];
  const float* lbih=(const float*)d_in[36],*lbhh=(const float*)d_in[37];
  const float* d1w=(const float*)d_in[38], *d1b=(const float*)d_in[39];
  const float* d2w=(const float*)d_in[40], *d2b=(const float*)d_in[41];
  const float* d3w=(const float*)d_in[42], *d3b=(const float*)d_in[43];
  const float* pw =(const float*)d_in[44], *pb =(const float*)d_in[45];
  float* ws = (float*)d_ws;
  int*   iw = (int*)(ws + OFF_FEND);
  float* outp = (float*)d_out;

  k_zero     <<<(OFF_SMIP+255)/256, 256, 0, stream>>>(ws, iw);
  k_prep     <<<(65536 + 198*132 + 198*68 + 255)/256, 256, 0, stream>>>(e1w, e2w, c1w, gwih, gwhh, ws);
  k_buildq   <<<(726*ID+255)/256, 256, 0, stream>>>(nnw, nnb, ws);
  k_csc      <<<(NN*NN)/256, 256, 0, stream>>>(adj, ws, iw);
  k_edge     <<<EE/EB, 256, 0, stream>>>(mnc, eidx, e1b, e2b, c1b, c2w, c2b, ws);
  k_node     <<<NN/NB, 256, 0, stream>>>(mnc, n1w,n1b, n2w,n2b, ws);
  k_bn_stats <<<ID, 256, 0, stream>>>(ws);
  k_bn_apply <<<(NN*ID+255)/256, 256, 0, stream>>>(bng, bnb, ws);
  for (int it=0; it<3; ++it){
    k_zero_magg<<<(NN*ID+255)/256, 256, 0, stream>>>(ws);
    k_msg    <<<EE/MEB, 256, 0, stream>>>(ea, eidx, ws);
    k_mnode  <<<NN/NB, 256, 0, stream>>>(root, nnbias, ws);
    k_spconv <<<NN, 256, 0, stream>>>(cv1w, cv1b, cv2w, cv2b, it, ws, iw);
    k_gru    <<<BB, 256, 0, stream>>>(mb, lfw, lfb, gbih, gbhh, ws);
  }
  k_s2s      <<<BB, 256, 0, stream>>>(mb, lwih, lwhh, lbih, lbhh, ws);
  k_fd1      <<<BB*16, 256, 0, stream>>>(fing, d1w, d1b, ws);
  k_fd2      <<<BB*8, 256, 0, stream>>>(d2w, d2b, ws);
  k_fd3p     <<<BB, 256, 0, stream>>>(d3w, d3b, pw, pb, ws, outp);
}